// Round 4
// baseline (1073.299 us; speedup 1.0000x reference)
//
#include <hip/hip_runtime.h>
#include <hip/hip_bf16.h>
#include <cstdint>

// Problem constants
#define BATCH 2048
#define MF    40                 // num fields
#define DDIM  64                 // embedding dim
#define LDIM  128                // hidden size per CIN layer
#define ROWS  (BATCH * DDIM)     // 131072 (b,d) rows

typedef __attribute__((ext_vector_type(4)))  short    short4_t;
typedef __attribute__((ext_vector_type(8)))  short    short8;
typedef __attribute__((ext_vector_type(8)))  __bf16   bf16x8;
typedef __attribute__((ext_vector_type(2)))  float    floatx2;
typedef __attribute__((ext_vector_type(16))) float    floatx16;

// POST-MORTEM LEDGER (do not revisit):
//  R1: t-split 4-blocks/CU REGRESSED 380->470. Halved per-wave tile -> 2x LDS
//      traffic (~57 TB/s), 4x barriers/MFMA, spilled at hard 128-reg cap.
//  R2: nontemporal hints REGRESSED 380->397. NT out-stores are scattered
//      dwords -> partial-line HBM writes (WRITE_SIZE 3->30 MB). NT only for
//      full-line streaming data (kept in k_wprep only).
//  R3: anti-phase stagger NEUTRAL (block phase isn't the gate); zero-C MFMA
//      init NEUTRAL (+8 VGPR, P-init not on critical path). Both reverted.
//  Invariant across R0-R3: matrix-pipe busy ~207 us, T ~2280 cyc/unit vs
//      ~1030 cyc/CU matrix demand at 8 waves/CU. This round: raise waves/CU
//      to 12 via ring-3 (48 KB LDS), per-wave code unchanged.

__device__ __forceinline__ unsigned short f32_to_bf16(float f) {
    union { float f; uint32_t u; } v; v.f = f;
    uint32_t u = v.u;
    uint32_t r = (u + 0x7fffu + ((u >> 16) & 1u)) >> 16;   // RNE
    return (unsigned short)r;
}

// raw barrier: execution sync WITHOUT __syncthreads' vmcnt(0)/lgkmcnt(0) drain
__device__ __forceinline__ void barrier_raw() {
    asm volatile("s_barrier" ::: "memory");
}
__device__ __forceinline__ void lgkmwait0() {
    asm volatile("s_waitcnt lgkmcnt(0)" ::: "memory");
}
template <int N> __device__ __forceinline__ void vmwait() {
    if constexpr (N == 0)  asm volatile("s_waitcnt vmcnt(0)"  ::: "memory");
    if constexpr (N == 6)  asm volatile("s_waitcnt vmcnt(6)"  ::: "memory");
}

// ---------------------------------------------------------------------------
// W prep, all three layers in ONE launch.
//   Wt[m][kk][cb][lane][j] = W[m][ kk*16 + (lane>>5)*8 + j ][ cb*32 + (lane&31) ]
// W0 padded to KK=4 (h in [40,64) -> 0). fp32 W reads NT (dead after this
// kernel, full-line streaming -> safe NT use).
// ---------------------------------------------------------------------------
__global__ void k_wprep_all(const float* __restrict__ W0, const float* __restrict__ W1,
                            const float* __restrict__ W2,
                            unsigned short* __restrict__ W0t,
                            unsigned short* __restrict__ W1t,
                            unsigned short* __restrict__ W2t) {
    int bi = blockIdx.x;                 // W0: 640 blocks, W1/W2: 1280 each
    const float* W; unsigned short* Wt; int KK, H;
    if (bi < 640)       { W = W0; Wt = W0t; KK = 4; H = 40; }
    else if (bi < 1920) { bi -= 640;  W = W1; Wt = W1t; KK = 8; H = 128; }
    else                { bi -= 1920; W = W2; Wt = W2t; KK = 8; H = 128; }
    int lane = threadIdx.x;
    int cb = bi & 3;
    int mkk = bi >> 2;
    int kk = mkk % KK, m = mkk / KK;
    int l = cb * 32 + (lane & 31);
    int hbase = kk * 16 + (lane >> 5) * 8;
    unsigned short o[8];
#pragma unroll
    for (int j = 0; j < 8; ++j) {
        int h = hbase + j;
        float v = (h < H) ? __builtin_nontemporal_load(&W[((size_t)m * H + h) * LDIM + l]) : 0.f;
        o[j] = f32_to_bf16(v);
    }
    *(short8*)(Wt + (((size_t)(m * KK + kk) * 4 + cb) * 64 + lane) * 8) = *(const short8*)o;
}

// ---------------------------------------------------------------------------
// One layer's K-loop: RING-3 variant of the proven raw-barrier/counted-vmcnt
// body. Per-wave instruction stream identical to the ring-4 version except
// slot addressing (rotating base ints c0/c1/c2) and the gate:
//   unit top (kk%4==0): barrier; stage(u+2) -> c2; [m-top: 2 scale loads]
//   gate vmcnt(6) at kk%4==1: guarantees stage(u+1) (issued top of u-1)
//     retired BEFORE its first ds_read at kk=2 of unit u (airtight; count =
//     scale(2)+stage(u+2)(4) issued after it, uniform for KK=4 and KK=8).
//   rotate bases at kk%4==3.
// Prologue: stage(0)->c0, stage(1)->c1, scale(m=0), vmcnt(0), barrier.
// ---------------------------------------------------------------------------
template <int KK>
__device__ __forceinline__ void layer_loop(
    const unsigned short* __restrict__ Wt,     // bf16 [MF][KK][4][64][8]
    const float* __restrict__ x, int b,
    int lane, int hf, int r31, int cbg0, int cbg1,
    unsigned short* slabf,                     // 3 slots x 8192 shorts (48 KB)
    bf16x8 (&xk)[2][8], floatx16 (&acc)[2][2])
{
    constexpr int UPM  = KK / 4;               // units per m
    constexpr int NU   = MF * UPM;             // total units (16 KB each)

    auto stage = [&](int uu, int sbase) {      // stage unit uu into slot base
        int u = uu < NU ? uu : NU - 1;         // clamp: same bytes, keeps count
        const unsigned short* src = Wt + (size_t)u * 8192;
        const int tid = threadIdx.x;
#pragma unroll
        for (int it = 0; it < 4; ++it) {
            int c = it * 256 + tid;
            __builtin_amdgcn_global_load_lds(
                (const __attribute__((address_space(1))) uint32_t*)(src + (size_t)c * 8),
                (__attribute__((address_space(3))) uint32_t*)(&slabf[(size_t)sbase + (size_t)c * 8]),
                16, 0, 0);
        }
    };
    auto ldfrag = [&](int sbase, int frag, int cb) {
        return __builtin_bit_cast(bf16x8, *(const short8*)(
            &slabf[(size_t)sbase + ((size_t)(frag * 4 + cb) * 64 + lane) * 8]));
    };

    acc[0][0] = floatx16{}; acc[0][1] = floatx16{};
    acc[1][0] = floatx16{}; acc[1][1] = floatx16{};

    int c0 = 0, c1 = 8192, c2 = 16384;         // rotating slot bases (shorts)

    // prologue: stage units 0,1; m=0 scale; full drain -> everything resident
    stage(0, c0); stage(1, c1);
    float s0n, s1n;
    {
        const float* sp = x + ((size_t)b * MF + 0) * DDIM + r31;
        s0n = sp[0];
        s1n = sp[32];
    }
    vmwait<0>();
    barrier_raw();

    bf16x8 bbuf[2][2];                         // W A-frag register ring
#pragma unroll
    for (int p = 0; p < 2; ++p) {
        bbuf[p][0] = ldfrag(c0, p, cbg0);
        bbuf[p][1] = ldfrag(c0, p, cbg1);
    }

    float s0v = 0.f, s1v = 0.f;

#pragma unroll 1
    for (int m = 0; m < MF; ++m) {
        floatx16 P[2][2] = {};
#pragma unroll
        for (int kk = 0; kk < KK; ++kk) {
            if (kk % 4 == 0) {                 // unit top
                barrier_raw();
                asm volatile("s_setprio 1");
                stage(m * UPM + kk / 4 + 2, c2);   // 2 units ahead, ring-3
                if (kk == 0) {                 // rotate scale ring; prefetch m+1
                    s0v = s0n; s1v = s1n;
                    const int mn = (m + 1 < MF) ? m + 1 : MF - 1;   // clamped dead load
                    const float* sp = x + ((size_t)b * MF + mn) * DDIM + r31;
                    s0n = sp[0];
                    s1n = sp[32];
                }
            }
            const int slot = kk & 1;
            P[0][0] = __builtin_amdgcn_mfma_f32_32x32x16_bf16(bbuf[slot][0], xk[0][kk], P[0][0], 0, 0, 0);
            P[1][0] = __builtin_amdgcn_mfma_f32_32x32x16_bf16(bbuf[slot][0], xk[1][kk], P[1][0], 0, 0, 0);
            P[0][1] = __builtin_amdgcn_mfma_f32_32x32x16_bf16(bbuf[slot][1], xk[0][kk], P[0][1], 0, 0, 0);
            P[1][1] = __builtin_amdgcn_mfma_f32_32x32x16_bf16(bbuf[slot][1], xk[1][kk], P[1][1], 0, 0, 0);
            {   // prefetch 2 kk ahead; kk%4>=2 crosses into the NEXT unit (c1)
                const int fr = (kk + 2) & 3;
                const int sb = ((kk & 3) >= 2) ? c1 : c0;
                bbuf[slot][0] = ldfrag(sb, fr, cbg0);
                bbuf[slot][1] = ldfrag(sb, fr, cbg1);
            }
            if (kk % 4 == 1) vmwait<6>();      // u+1 resident before kk=2 reads
            if (kk % 4 == 3) {                 // rotate ring at unit end
                int tmp = c0; c0 = c1; c1 = c2; c2 = tmp;
            }
        }
        asm volatile("s_setprio 0");
        // epilogue: acc += s_t * P (float2 -> v_pk_fma_f32)
#pragma unroll
        for (int t = 0; t < 2; ++t) {
            const float sv = (t == 0) ? s0v : s1v;
            floatx2 s2 = {sv, sv};
#pragma unroll
            for (int cbp = 0; cbp < 2; ++cbp) {
                floatx2*       A = (floatx2*)&acc[t][cbp];
                const floatx2* Q = (const floatx2*)&P[t][cbp];
#pragma unroll
                for (int i = 0; i < 8; ++i) A[i] += s2 * Q[i];
            }
        }
    }
}

// ---------------------------------------------------------------------------
// Fused 3-layer CIN kernel. Block = 256 thr = 4 waves (2x2), 2 batches x all
// 128 l's per block. X intermediates never touch global (LDS exchange in
// slots 0-1); ps fused per layer (butterfly shuffle).
//
// R4: RING-3 W-buffer -> LDS 48 KB/block -> 3 blocks/CU (12 waves/CU), with
// the per-wave instruction stream unchanged. VGPR_Count 120 <= 128 bucket
// permits 16 waves/CU, so R0 was LDS-capped, not reg-capped. Matrix demand
// per CU per unit rises 1033 -> 1550 cyc; if the idle was coverable latency,
// MfmaUtil 54 -> ~70.
// ---------------------------------------------------------------------------
__global__ __launch_bounds__(256, 3) void k_cin(
    const float* __restrict__ x,               // fp32 [B][MF][DDIM]
    const unsigned short* __restrict__ W0t,    // bf16 [MF][4][4][64][8] (padded)
    const unsigned short* __restrict__ W1t,    // bf16 [MF][8][4][64][8]
    const unsigned short* __restrict__ W2t,    // bf16 [MF][8][4][64][8]
    float* __restrict__ out)                   // fp32 [B][384]
{
    __shared__ unsigned short slab[3][8192];   // 3 x 16 KB W-ring; slots 0-1
                                               // double as the 32 KB X-exchange
    unsigned short* slabf = &slab[0][0];

    const int tid  = threadIdx.x;
    const int lane = tid & 63, wave = tid >> 6;
    const int hf   = lane >> 5, r31 = lane & 31;
    const int rowhalf = wave >> 1, colhalf = wave & 1;
    const int b = blockIdx.x * 2 + rowhalf;    // this wave's batch
    const int cbg0 = colhalf * 2, cbg1 = colhalf * 2 + 1;

    bf16x8   xk[2][8];                         // B-operand fragments
    floatx16 acc[2][2];                        // [t(row-tile)][cbp], D[l,row]

    // ---- ps: out[b][OFF+l] = sum over all 64 d (butterfly across lanes) ----
    auto write_ps = [&](int OFF) {
#pragma unroll
        for (int cbp = 0; cbp < 2; ++cbp) {
#pragma unroll
            for (int j = 0; j < 16; ++j) {
                float v = acc[0][cbp][j] + acc[1][cbp][j];
                v += __shfl_xor(v, 16);
                v += __shfl_xor(v, 8);
                v += __shfl_xor(v, 4);
                v += __shfl_xor(v, 2);
                v += __shfl_xor(v, 1);
                if (r31 == 0)
                    out[(size_t)b * 384 + OFF + (colhalf * 2 + cbp) * 32 +
                        (j & 3) + 8 * (j >> 2) + 4 * hf] = v;
            }
        }
    };

    // ---- layer boundary: acc -> LDS (reader frag order) -> xk ----
    // Writer element: row = t*32+r31, l = colhalf*64 + cbp*32 + 8g + 4hf + i
    //   => kk = colhalf*4 + cbp*2 + (g>>1), hfr = g&1, j = 4hf+i
    // Xf addr (shorts): rowhalf*8192 + ((t*8+kk)*64 + hfr*32 + r31)*8 + 4hf
    auto exchange = [&]() {
        vmwait<0>();                           // drain ring staging + ps stores
        barrier_raw();
#pragma unroll
        for (int t = 0; t < 2; ++t)
#pragma unroll
            for (int cbp = 0; cbp < 2; ++cbp)
#pragma unroll
                for (int g = 0; g < 4; ++g) {
                    unsigned short o[4];
#pragma unroll
                    for (int i = 0; i < 4; ++i) o[i] = f32_to_bf16(acc[t][cbp][g * 4 + i]);
                    const int kk  = colhalf * 4 + cbp * 2 + (g >> 1);
                    const int hfr = g & 1;
                    *(short4_t*)(&slabf[(size_t)rowhalf * 8192 +
                        ((size_t)(t * 8 + kk) * 64 + hfr * 32 + r31) * 8 + 4 * hf]) =
                        *(const short4_t*)o;
                }
        lgkmwait0();                           // writes committed to LDS
        barrier_raw();
#pragma unroll
        for (int t = 0; t < 2; ++t)
#pragma unroll
            for (int kk = 0; kk < 8; ++kk)
                xk[t][kk] = __builtin_bit_cast(bf16x8, *(const short8*)(
                    &slabf[(size_t)rowhalf * 8192 + ((size_t)(t * 8 + kk) * 64 + lane) * 8]));
        lgkmwait0();                           // reads in regs before restaging
        barrier_raw();
    };

    // ---- layer 0: xk from original x (KK=4 padded, h<MF else 0) ----
#pragma unroll
    for (int t = 0; t < 2; ++t)
#pragma unroll
        for (int kk = 0; kk < 4; ++kk) {
            unsigned short tmp[8];
#pragma unroll
            for (int j = 0; j < 8; ++j) {
                int h = kk * 16 + hf * 8 + j;
                float v = (h < MF) ? x[((size_t)b * MF + h) * DDIM + t * 32 + r31] : 0.f;
                tmp[j] = f32_to_bf16(v);
            }
            xk[t][kk] = __builtin_bit_cast(bf16x8, *(const short8*)tmp);
        }

    layer_loop<4>(W0t, x, b, lane, hf, r31, cbg0, cbg1, slabf, xk, acc);
    write_ps(0);
    exchange();

    layer_loop<8>(W1t, x, b, lane, hf, r31, cbg0, cbg1, slabf, xk, acc);
    write_ps(128);
    exchange();

    layer_loop<8>(W2t, x, b, lane, hf, r31, cbg0, cbg1, slabf, xk, acc);
    write_ps(256);
}

// ---------------------------------------------------------------------------
extern "C" void kernel_launch(void* const* d_in, const int* in_sizes, int n_in,
                              void* d_out, int out_size, void* d_ws, size_t ws_size,
                              hipStream_t stream) {
    const float* x  = (const float*)d_in[0];
    const float* W0 = (const float*)d_in[1];
    const float* W1 = (const float*)d_in[2];
    const float* W2 = (const float*)d_in[3];
    float* out = (float*)d_out;

    char* ws = (char*)d_ws;
    size_t off = 0;
    auto alloc = [&](size_t bytes) -> void* {
        void* p = ws + off;
        off += (bytes + 255) & ~(size_t)255;
        return p;
    };
    unsigned short* W0t = (unsigned short*)alloc((size_t)MF * 4 * 2048 * 2);   // 0.66 MB
    unsigned short* W1t = (unsigned short*)alloc((size_t)MF * 8 * 2048 * 2);   // 1.31 MB
    unsigned short* W2t = (unsigned short*)alloc((size_t)MF * 8 * 2048 * 2);   // 1.31 MB

    k_wprep_all<<<3200, 64, 0, stream>>>(W0, W1, W2, W0t, W1t, W2t);
    k_cin<<<ROWS / 128, 256, 0, stream>>>(x, W0t, W1t, W2t, out);
}

// Round 6
// 450.684 us; speedup vs baseline: 2.3815x; 2.3815x over previous
//
#include <hip/hip_runtime.h>
#include <hip/hip_bf16.h>
#include <cstdint>

// Problem constants
#define BATCH 2048
#define MF    40                 // num fields
#define DDIM  64                 // embedding dim
#define LDIM  128                // hidden size per CIN layer
#define ROWS  (BATCH * DDIM)     // 131072 (b,d) rows

typedef __attribute__((ext_vector_type(4)))  short    short4_t;
typedef __attribute__((ext_vector_type(8)))  short    short8;
typedef __attribute__((ext_vector_type(8)))  __bf16   bf16x8;
typedef __attribute__((ext_vector_type(2)))  float    floatx2;
typedef __attribute__((ext_vector_type(4)))  float    floatx4;
typedef __attribute__((ext_vector_type(16))) float    floatx16;

// POST-MORTEM LEDGER (do not revisit):
//  R1: t-split 4-blocks/CU REGRESSED 380->470. Halved per-wave tile -> 2x LDS
//      traffic (~57 TB/s), 4x barriers/MFMA, spilled at hard 128-reg cap.
//  R2: nontemporal hints REGRESSED 380->397. NT out-stores are scattered
//      dwords -> partial-line HBM writes (WRITE_SIZE 3->30 MB). NT only for
//      full-line streaming data (kept in k_wprep only).
//  R3: anti-phase stagger NEUTRAL (block phase isn't the gate); zero-C MFMA
//      init NEUTRAL (P-init not on critical path). Both reverted.
//  R4: ring-3 (48KB, launch_bounds(256,3)) CATASTROPHIC 380->1073.
//      Runtime-rotating slot bases -> runtime LDS addressing -> spill
//      (FETCH 36MB->1.79GB, WRITE 3->155MB scratch). Ring depth must be
//      power-of-2 with compile-time (u&3) addressing; >2 waves/SIMD caps
//      spill this body (3rd confirmation). Occupancy line of inquiry CLOSED.
//  R5: compile fail — __builtin_nontemporal_load needs clang ext_vector
//      types, NOT HIP_vector_type float4. Use floatx4 typedef.
//  Invariant across R0-R4: k_cin matrix-pipe busy ~207 us vs 171 us floor,
//      T~2280 cyc/unit, 45% idle unexplained; VALUBusy 26% (~150 inst/unit/
//      wave) is the anomaly to ablate if in-loop work resumes.
//  R6 (this round): = R5 with the typedef fix. k_cin byte-exact R0; wprep
//      coalesced (800x256, LDS transpose) to attack the 43-55 us bench-vs-
//      k_cin gap; if gap persists, it's harness overhead, not wprep.

__device__ __forceinline__ unsigned short f32_to_bf16(float f) {
    union { float f; uint32_t u; } v; v.f = f;
    uint32_t u = v.u;
    uint32_t r = (u + 0x7fffu + ((u >> 16) & 1u)) >> 16;   // RNE
    return (unsigned short)r;
}

// raw barrier: execution sync WITHOUT __syncthreads' vmcnt(0)/lgkmcnt(0) drain
__device__ __forceinline__ void barrier_raw() {
    asm volatile("s_barrier" ::: "memory");
}
__device__ __forceinline__ void lgkmwait0() {
    asm volatile("s_waitcnt lgkmcnt(0)" ::: "memory");
}
template <int N> __device__ __forceinline__ void vmwait() {
    if constexpr (N == 0)  asm volatile("s_waitcnt vmcnt(0)"  ::: "memory");
    if constexpr (N == 4)  asm volatile("s_waitcnt vmcnt(4)"  ::: "memory");
    if constexpr (N == 6)  asm volatile("s_waitcnt vmcnt(6)"  ::: "memory");
    if constexpr (N == 10) asm volatile("s_waitcnt vmcnt(10)" ::: "memory");
}

// ---------------------------------------------------------------------------
// W prep, coalesced rewrite. One block per (layer, m, kk) 16h x 128l tile:
// 800 blocks x 256 threads (was 3200 x 64 with half-coalesced scalar loads).
// Path: floatx4 coalesced load -> bf16 LDS tile [16][128] -> per-lane short8
// gather -> 1 KB/wave contiguous store. Same output layout as ever:
//   Wt[m][kk][cb][lane][j] = W[m][ kk*16 + (lane>>5)*8 + j ][ cb*32 + (lane&31) ]
// W0 padded to KK=4 (h in [40,64) -> 0). NT on the f32 W reads (dead after).
// ---------------------------------------------------------------------------
__global__ __launch_bounds__(256) void k_wprep_all(
    const float* __restrict__ W0, const float* __restrict__ W1,
    const float* __restrict__ W2,
    unsigned short* __restrict__ W0t,
    unsigned short* __restrict__ W1t,
    unsigned short* __restrict__ W2t) {
    __shared__ unsigned short t16[16 * 128];   // bf16 tile [h_local][l]

    int bi = blockIdx.x;                 // W0: 160 tiles, W1/W2: 320 each
    const float* W; unsigned short* Wt; int KK, H;
    if (bi < 160)      { W = W0; Wt = W0t; KK = 4; H = 40; }
    else if (bi < 480) { bi -= 160; W = W1; Wt = W1t; KK = 8; H = 128; }
    else               { bi -= 480; W = W2; Wt = W2t; KK = 8; H = 128; }
    const int tid = threadIdx.x;
    const int kk = bi % KK, m = bi / KK;

    // load + convert: 2048 f32 (16 rows x 128), 2 floatx4 per thread, row-
    // granular validity (32 threads per 128-elem row; no floatx4 straddles).
#pragma unroll
    for (int half = 0; half < 2; ++half) {
        const int idx = half * 1024 + tid * 4;      // tile-linear f32 index
        const int hl  = idx >> 7, l = idx & 127;
        const int hg  = kk * 16 + hl;
        floatx4 v = {0.f, 0.f, 0.f, 0.f};
        if (hg < H)
            v = __builtin_nontemporal_load(
                (const floatx4*)&W[((size_t)m * H + hg) * LDIM + l]);
        unsigned short o[4];
        o[0] = f32_to_bf16(v.x); o[1] = f32_to_bf16(v.y);
        o[2] = f32_to_bf16(v.z); o[3] = f32_to_bf16(v.w);
        *(short4_t*)&t16[idx] = *(const short4_t*)o;
    }
    __syncthreads();

    // gather + store: lane's short8 = 8 consecutive h at fixed l.
    const int lane = tid & 63, cb = tid >> 6;
    const int l  = cb * 32 + (lane & 31);
    const int hb = (lane >> 5) * 8;
    unsigned short o[8];
#pragma unroll
    for (int j = 0; j < 8; ++j) o[j] = t16[(hb + j) * 128 + l];
    *(short8*)(Wt + (((size_t)(m * KK + kk) * 4 + cb) * 64 + lane) * 8) =
        *(const short8*)o;
}

// ---------------------------------------------------------------------------
// One layer's K-loop: the proven ring-4 / raw-barrier / counted-vmcnt body
// (byte-exact R0). Operand-swapped: W = A-operand, XK = B-operand ->
// D[l, row]; per-row scale s_m is a per-lane scalar applied in a tiny
// float2 epilogue. KK=4 (L0, UPM=1, gate 6) or KK=8 (L1/L2, UPM=2, gate 10).
// ---------------------------------------------------------------------------
template <int KK>
__device__ __forceinline__ void layer_loop(
    const unsigned short* __restrict__ Wt,     // bf16 [MF][KK][4][64][8]
    const float* __restrict__ x, int b,
    int lane, int hf, int r31, int cbg0, int cbg1,
    unsigned short* slabf,                     // &slab[0][0]: 4 slots x 8192 shorts
    bf16x8 (&xk)[2][8], floatx16 (&acc)[2][2])
{
    constexpr int UPM  = KK / 4;               // units per m
    constexpr int NU   = MF * UPM;             // total units (16 KB each)
    constexpr int GATE = (KK == 8) ? 10 : 6;   // = vmem insts per m (uniform)

    auto stage = [&](int uu) {                 // stage unit uu (clamped: same bytes)
        int u = uu < NU ? uu : NU - 1;
        const unsigned short* src = Wt + (size_t)u * 8192;
        const int tid = threadIdx.x;
#pragma unroll
        for (int it = 0; it < 4; ++it) {
            int c = it * 256 + tid;
            __builtin_amdgcn_global_load_lds(
                (const __attribute__((address_space(1))) uint32_t*)(src + (size_t)c * 8),
                (__attribute__((address_space(3))) uint32_t*)(&slabf[(size_t)(u & 3) * 8192 + (size_t)c * 8]),
                16, 0, 0);
        }
    };
    auto ldfrag = [&](int u, int frag, int cb) {
        return __builtin_bit_cast(bf16x8, *(const short8*)(
            &slabf[(size_t)(u & 3) * 8192 + ((size_t)(frag * 4 + cb) * 64 + lane) * 8]));
    };

    acc[0][0] = floatx16{}; acc[0][1] = floatx16{};
    acc[1][0] = floatx16{}; acc[1][1] = floatx16{};

    // prologue: fill 3 ring slots; units 0,1 retired before priming
    vmwait<0>();
    stage(0); stage(1); stage(2);
    vmwait<4>();
    barrier_raw();

    bf16x8 bbuf[2][2];                         // W A-frag register ring
#pragma unroll
    for (int p = 0; p < 2; ++p) {
        bbuf[p][0] = ldfrag(0, p, cbg0);
        bbuf[p][1] = ldfrag(0, p, cbg1);
    }

    float s0v = 0.f, s1v = 0.f;

#pragma unroll 1
    for (int m = 0; m < MF; ++m) {
        floatx16 P[2][2] = {};
#pragma unroll
        for (int kk = 0; kk < KK; ++kk) {
            if (kk % 4 == 0) {                 // unit top
                barrier_raw();
                asm volatile("s_setprio 1");
                if (kk == 0) {                 // 2 per-lane scalar scale loads
                    const float* sp = x + ((size_t)b * MF + m) * DDIM + r31;
                    s0v = sp[0];
                    s1v = sp[32];
                }
                stage(m * UPM + kk / 4 + 3);   // 3 units ahead in the ring
            }
            const int slot = kk & 1;
            P[0][0] = __builtin_amdgcn_mfma_f32_32x32x16_bf16(bbuf[slot][0], xk[0][kk], P[0][0], 0, 0, 0);
            P[1][0] = __builtin_amdgcn_mfma_f32_32x32x16_bf16(bbuf[slot][0], xk[1][kk], P[1][0], 0, 0, 0);
            P[0][1] = __builtin_amdgcn_mfma_f32_32x32x16_bf16(bbuf[slot][1], xk[0][kk], P[0][1], 0, 0, 0);
            P[1][1] = __builtin_amdgcn_mfma_f32_32x32x16_bf16(bbuf[slot][1], xk[1][kk], P[1][1], 0, 0, 0);
            {   // prefetch 2 kk ahead (crosses unit/m boundary; all compile-time)
                const int j  = kk + 2;
                int mm = m + ((j >= KK) ? 1 : 0);
                if (mm > MF - 1) mm = MF - 1;
                const int jj = (j >= KK) ? (j - KK) : j;
                const int u  = mm * UPM + jj / 4;
                bbuf[slot][0] = ldfrag(u, jj % 4, cbg0);
                bbuf[slot][1] = ldfrag(u, jj % 4, cbg1);
            }
            if (kk % 4 == 3) vmwait<GATE>();   // uniform end-of-unit gate
        }
        asm volatile("s_setprio 0");
        // epilogue: acc += s_t * P (float2 -> v_pk_fma_f32)
#pragma unroll
        for (int t = 0; t < 2; ++t) {
            const float sv = (t == 0) ? s0v : s1v;
            floatx2 s2 = {sv, sv};
#pragma unroll
            for (int cbp = 0; cbp < 2; ++cbp) {
                floatx2*       A = (floatx2*)&acc[t][cbp];
                const floatx2* Q = (const floatx2*)&P[t][cbp];
#pragma unroll
                for (int i = 0; i < 8; ++i) A[i] += s2 * Q[i];
            }
        }
    }
}

// ---------------------------------------------------------------------------
// Fused 3-layer CIN kernel. Block = 256 thr = 4 waves (2x2), 2 batches x all
// 128 l's per block; grid 1024 = 2 blocks/CU. X intermediates NEVER touch
// global: at each layer boundary, waves write their D-layout acc into LDS
// (overlaying ring slots 0-1) in exact reader B-fragment order, then reload
// xk fragments. ps outputs fused per layer (butterfly shuffle).
// NOTE: (256,2) -> 256 unified regs/wave. (512,4) spilled catastrophically;
// (256,4) t-split failed R1; (256,3) ring-3 spilled R4. Do not revisit.
// ---------------------------------------------------------------------------
__global__ __launch_bounds__(256, 2) void k_cin(
    const float* __restrict__ x,               // fp32 [B][MF][DDIM]
    const unsigned short* __restrict__ W0t,    // bf16 [MF][4][4][64][8] (padded)
    const unsigned short* __restrict__ W1t,    // bf16 [MF][8][4][64][8]
    const unsigned short* __restrict__ W2t,    // bf16 [MF][8][4][64][8]
    float* __restrict__ out)                   // fp32 [B][384]
{
    __shared__ unsigned short slab[4][8192];   // 4 x 16 KB W-ring; slots 0-1
                                               // double as the 32 KB X-exchange
    unsigned short* slabf = &slab[0][0];

    const int tid  = threadIdx.x;
    const int lane = tid & 63, wave = tid >> 6;
    const int hf   = lane >> 5, r31 = lane & 31;
    const int rowhalf = wave >> 1, colhalf = wave & 1;
    const int b = blockIdx.x * 2 + rowhalf;    // this wave's batch
    const int cbg0 = colhalf * 2, cbg1 = colhalf * 2 + 1;

    bf16x8   xk[2][8];                         // B-operand fragments
    floatx16 acc[2][2];                        // [t(row-tile)][cbp], D[l,row]

    // ---- ps: out[b][OFF+l] = sum over all 64 d (butterfly across lanes) ----
    auto write_ps = [&](int OFF) {
#pragma unroll
        for (int cbp = 0; cbp < 2; ++cbp) {
#pragma unroll
            for (int j = 0; j < 16; ++j) {
                float v = acc[0][cbp][j] + acc[1][cbp][j];
                v += __shfl_xor(v, 16);
                v += __shfl_xor(v, 8);
                v += __shfl_xor(v, 4);
                v += __shfl_xor(v, 2);
                v += __shfl_xor(v, 1);
                if (r31 == 0)
                    out[(size_t)b * 384 + OFF + (colhalf * 2 + cbp) * 32 +
                        (j & 3) + 8 * (j >> 2) + 4 * hf] = v;
            }
        }
    };

    // ---- layer boundary: acc -> LDS (reader frag order) -> xk ----
    // Writer element: row = t*32+r31, l = colhalf*64 + cbp*32 + 8g + 4hf + i
    //   => kk = colhalf*4 + cbp*2 + (g>>1), hfr = g&1, j = 4hf+i
    // Xf addr (shorts): rowhalf*8192 + ((t*8+kk)*64 + hfr*32 + r31)*8 + 4hf
    auto exchange = [&]() {
        vmwait<0>();                           // drain ring staging + ps stores
        barrier_raw();
#pragma unroll
        for (int t = 0; t < 2; ++t)
#pragma unroll
            for (int cbp = 0; cbp < 2; ++cbp)
#pragma unroll
                for (int g = 0; g < 4; ++g) {
                    unsigned short o[4];
#pragma unroll
                    for (int i = 0; i < 4; ++i) o[i] = f32_to_bf16(acc[t][cbp][g * 4 + i]);
                    const int kk  = colhalf * 4 + cbp * 2 + (g >> 1);
                    const int hfr = g & 1;
                    *(short4_t*)(&slabf[(size_t)rowhalf * 8192 +
                        ((size_t)(t * 8 + kk) * 64 + hfr * 32 + r31) * 8 + 4 * hf]) =
                        *(const short4_t*)o;
                }
        lgkmwait0();                           // writes committed to LDS
        barrier_raw();
#pragma unroll
        for (int t = 0; t < 2; ++t)
#pragma unroll
            for (int kk = 0; kk < 8; ++kk)
                xk[t][kk] = __builtin_bit_cast(bf16x8, *(const short8*)(
                    &slabf[(size_t)rowhalf * 8192 + ((size_t)(t * 8 + kk) * 64 + lane) * 8]));
        lgkmwait0();                           // reads in regs before restaging
        barrier_raw();
    };

    // ---- layer 0: xk from original x (KK=4 padded, h<MF else 0) ----
#pragma unroll
    for (int t = 0; t < 2; ++t)
#pragma unroll
        for (int kk = 0; kk < 4; ++kk) {
            unsigned short tmp[8];
#pragma unroll
            for (int j = 0; j < 8; ++j) {
                int h = kk * 16 + hf * 8 + j;
                float v = (h < MF) ? x[((size_t)b * MF + h) * DDIM + t * 32 + r31] : 0.f;
                tmp[j] = f32_to_bf16(v);
            }
            xk[t][kk] = __builtin_bit_cast(bf16x8, *(const short8*)tmp);
        }

    layer_loop<4>(W0t, x, b, lane, hf, r31, cbg0, cbg1, slabf, xk, acc);
    write_ps(0);
    exchange();

    layer_loop<8>(W1t, x, b, lane, hf, r31, cbg0, cbg1, slabf, xk, acc);
    write_ps(128);
    exchange();

    layer_loop<8>(W2t, x, b, lane, hf, r31, cbg0, cbg1, slabf, xk, acc);
    write_ps(256);
}

// ---------------------------------------------------------------------------
extern "C" void kernel_launch(void* const* d_in, const int* in_sizes, int n_in,
                              void* d_out, int out_size, void* d_ws, size_t ws_size,
                              hipStream_t stream) {
    const float* x  = (const float*)d_in[0];
    const float* W0 = (const float*)d_in[1];
    const float* W1 = (const float*)d_in[2];
    const float* W2 = (const float*)d_in[3];
    float* out = (float*)d_out;

    char* ws = (char*)d_ws;
    size_t off = 0;
    auto alloc = [&](size_t bytes) -> void* {
        void* p = ws + off;
        off += (bytes + 255) & ~(size_t)255;
        return p;
    };
    unsigned short* W0t = (unsigned short*)alloc((size_t)MF * 4 * 2048 * 2);   // 0.66 MB
    unsigned short* W1t = (unsigned short*)alloc((size_t)MF * 8 * 2048 * 2);   // 1.31 MB
    unsigned short* W2t = (unsigned short*)alloc((size_t)MF * 8 * 2048 * 2);   // 1.31 MB

    k_wprep_all<<<800, 256, 0, stream>>>(W0, W1, W2, W0t, W1t, W2t);
    k_cin<<<ROWS / 128, 256, 0, stream>>>(x, W0t, W1t, W2t, out);
}

// Round 7
// 432.934 us; speedup vs baseline: 2.4791x; 1.0410x over previous
//
#include <hip/hip_runtime.h>
#include <hip/hip_bf16.h>
#include <cstdint>

// Problem constants
#define BATCH 2048
#define MF    40                 // num fields
#define DDIM  64                 // embedding dim
#define LDIM  128                // hidden size per CIN layer
#define ROWS  (BATCH * DDIM)     // 131072 (b,d) rows

typedef __attribute__((ext_vector_type(4)))  short    short4_t;
typedef __attribute__((ext_vector_type(8)))  short    short8;
typedef __attribute__((ext_vector_type(8)))  __bf16   bf16x8;
typedef __attribute__((ext_vector_type(2)))  float    floatx2;
typedef __attribute__((ext_vector_type(4)))  float    floatx4;
typedef __attribute__((ext_vector_type(16))) float    floatx16;

// POST-MORTEM LEDGER (do not revisit):
//  R1: t-split 4-blocks/CU REGRESSED 380->470 (2x LDS traffic, 4x barriers,
//      spill at 128-reg cap). Occupancy is NOT the lever.
//  R2: NT hints REGRESSED (scattered NT dword stores -> partial-line HBM
//      writes; NT loads evict re-read x). NT only in k_wprep.
//  R3: anti-phase stagger NEUTRAL; zero-C MFMA init NEUTRAL. Reverted.
//  R4: ring-3 + launch_bounds(256,3) CATASTROPHIC (runtime slot bases ->
//      spill, FETCH 1.79GB). Ring addressing must be compile-time (&3);
//      >2 waves/SIMD caps spill this body. Occupancy CLOSED.
//  R5: __builtin_nontemporal_load needs clang ext_vector, not HIP float4.
//  R6: coalesced wprep landed; bench-total minus k_cin gap (~55us) UNCHANGED
//      -> gap is fixed harness/launch overhead, not wprep. Cross-session
//      noise on identical code: +-2-3% (380 vs 393 us).
//  Invariant R0-R6: k_cin MFMA busy ~45-55% of wall, T~2280 cyc/unit vs
//      1024 cyc/CU MFMA demand; idle resists wave/cache-level fixes.
//  R7 (this round): 2-UNIT PHASES. Barrier every 32 MFMAs (was 16); gates
//      moved mid-burst (vmcnt(G1)@pkk1, vmcnt(4)@pkk5, in-order-retire
//      derivation); ring-4 16KB slots + compile-time addressing unchanged;
//      MFMA order unchanged (absmax must stay 16777220 exactly).

__device__ __forceinline__ unsigned short f32_to_bf16(float f) {
    union { float f; uint32_t u; } v; v.f = f;
    uint32_t u = v.u;
    uint32_t r = (u + 0x7fffu + ((u >> 16) & 1u)) >> 16;   // RNE
    return (unsigned short)r;
}

// raw barrier: execution sync WITHOUT __syncthreads' vmcnt(0)/lgkmcnt(0) drain
__device__ __forceinline__ void barrier_raw() {
    asm volatile("s_barrier" ::: "memory");
}
__device__ __forceinline__ void lgkmwait0() {
    asm volatile("s_waitcnt lgkmcnt(0)" ::: "memory");
}
template <int N> __device__ __forceinline__ void vmwait() {
    if constexpr (N == 0)  asm volatile("s_waitcnt vmcnt(0)"  ::: "memory");
    if constexpr (N == 4)  asm volatile("s_waitcnt vmcnt(4)"  ::: "memory");
    if constexpr (N == 10) asm volatile("s_waitcnt vmcnt(10)" ::: "memory");
    if constexpr (N == 12) asm volatile("s_waitcnt vmcnt(12)" ::: "memory");
}

// ---------------------------------------------------------------------------
// W prep, coalesced (R6, working). One block per (layer, m, kk) 16h x 128l
// tile: 800 x 256. floatx4 NT load -> bf16 LDS tile -> short8 store.
//   Wt[m][kk][cb][lane][j] = W[m][ kk*16 + (lane>>5)*8 + j ][ cb*32 + (lane&31) ]
// W0 padded to KK=4 (h in [40,64) -> 0).
// ---------------------------------------------------------------------------
__global__ __launch_bounds__(256) void k_wprep_all(
    const float* __restrict__ W0, const float* __restrict__ W1,
    const float* __restrict__ W2,
    unsigned short* __restrict__ W0t,
    unsigned short* __restrict__ W1t,
    unsigned short* __restrict__ W2t) {
    __shared__ unsigned short t16[16 * 128];   // bf16 tile [h_local][l]

    int bi = blockIdx.x;                 // W0: 160 tiles, W1/W2: 320 each
    const float* W; unsigned short* Wt; int KK, H;
    if (bi < 160)      { W = W0; Wt = W0t; KK = 4; H = 40; }
    else if (bi < 480) { bi -= 160; W = W1; Wt = W1t; KK = 8; H = 128; }
    else               { bi -= 480; W = W2; Wt = W2t; KK = 8; H = 128; }
    const int tid = threadIdx.x;
    const int kk = bi % KK, m = bi / KK;

#pragma unroll
    for (int half = 0; half < 2; ++half) {
        const int idx = half * 1024 + tid * 4;      // tile-linear f32 index
        const int hl  = idx >> 7, l = idx & 127;
        const int hg  = kk * 16 + hl;
        floatx4 v = {0.f, 0.f, 0.f, 0.f};
        if (hg < H)
            v = __builtin_nontemporal_load(
                (const floatx4*)&W[((size_t)m * H + hg) * LDIM + l]);
        unsigned short o[4];
        o[0] = f32_to_bf16(v.x); o[1] = f32_to_bf16(v.y);
        o[2] = f32_to_bf16(v.z); o[3] = f32_to_bf16(v.w);
        *(short4_t*)&t16[idx] = *(const short4_t*)o;
    }
    __syncthreads();

    const int lane = tid & 63, cb = tid >> 6;
    const int l  = cb * 32 + (lane & 31);
    const int hb = (lane >> 5) * 8;
    unsigned short o[8];
#pragma unroll
    for (int j = 0; j < 8; ++j) o[j] = t16[(hb + j) * 128 + l];
    *(short8*)(Wt + (((size_t)(m * KK + kk) * 4 + cb) * 64 + lane) * 8) =
        *(const short8*)o;
}

// ---------------------------------------------------------------------------
// One layer's K-loop: 2-UNIT-PHASE variant of the proven ring-4 body.
// Phase = 2 consecutive 16 KB units (8 kk, 32 MFMAs): one barrier per phase
// (halved vs R0), stage BOTH u+2,u+3 at phase top, gates mid-burst:
//   issue order/phase: scales (2*MPP) -> stage u+2 (4) -> stage u+3 (4)
//   vmcnt(G1=8+2*MPP) @pkk==1: prior phase's stages retired before pkk==2
//     reads of unit u+1 (G1 = exactly this phase's outstanding issues).
//   vmcnt(4) @pkk==5: u+2's stage retired before its pkk==6 prefetch
//     (only u+3's 4 stages may remain; VMEM retires in order).
// Slot addressing stays compile-time-shaped: base=(2p)&3 (uniform SALU),
// offsets constant (R4 lesson). Tail stages clamp to NU-1 (same-bytes,
// benign); tail prefetches read dead data (never consumed).
// Epilogue per m unchanged: acc += s_m * P (v_pk_fma_f32).
// ---------------------------------------------------------------------------
template <int KK>
__device__ __forceinline__ void layer_loop(
    const unsigned short* __restrict__ Wt,     // bf16 [MF][KK][4][64][8]
    const float* __restrict__ x, int b,
    int lane, int hf, int r31, int cbg0, int cbg1,
    unsigned short* slabf,                     // 4 slots x 8192 shorts
    bf16x8 (&xk)[2][8], floatx16 (&acc)[2][2])
{
    constexpr int UPM = KK / 4;                // units per m (1 or 2)
    constexpr int MPP = 2 / UPM;               // m per phase (2 or 1)
    constexpr int NU  = MF * UPM;              // 40 or 80 (even)
    constexpr int NP  = NU / 2;                // phases: 20 or 40
    constexpr int G1  = 8 + 2 * MPP;           // phase-top vmem issues (12/10)

    auto stage = [&](int uu, int slot) {       // stage unit uu into slot
        int u = uu < NU ? uu : NU - 1;         // clamp: same bytes, keeps count
        const unsigned short* src = Wt + (size_t)u * 8192;
        const int tid = threadIdx.x;
#pragma unroll
        for (int it = 0; it < 4; ++it) {
            int c = it * 256 + tid;
            __builtin_amdgcn_global_load_lds(
                (const __attribute__((address_space(1))) uint32_t*)(src + (size_t)c * 8),
                (__attribute__((address_space(3))) uint32_t*)(&slabf[(size_t)slot * 8192 + (size_t)c * 8]),
                16, 0, 0);
        }
    };
    auto ldfrag = [&](int slot, int frag, int cb) {
        return __builtin_bit_cast(bf16x8, *(const short8*)(
            &slabf[(size_t)slot * 8192 + ((size_t)(frag * 4 + cb) * 64 + lane) * 8]));
    };

    acc[0][0] = floatx16{}; acc[0][1] = floatx16{};
    acc[1][0] = floatx16{}; acc[1][1] = floatx16{};

    // prologue: stage units 0,1 into slots 0,1; full drain; prime bbuf
    vmwait<0>();
    stage(0, 0); stage(1, 1);
    vmwait<0>();
    barrier_raw();

    bf16x8 bbuf[2][2];                         // W A-frag register ring
#pragma unroll
    for (int pfr = 0; pfr < 2; ++pfr) {
        bbuf[pfr][0] = ldfrag(0, pfr, cbg0);
        bbuf[pfr][1] = ldfrag(0, pfr, cbg1);
    }

#pragma unroll 1
    for (int p = 0; p < NP; ++p) {
        const int base = (2 * p) & 3;          // slot of this phase's 1st unit
        float s0v[MPP], s1v[MPP];

        barrier_raw();
        asm volatile("s_setprio 1");
#pragma unroll
        for (int mi = 0; mi < MPP; ++mi) {     // this phase's per-m scales
            const float* sp = x + ((size_t)b * MF + (p * MPP + mi)) * DDIM + r31;
            s0v[mi] = sp[0];
            s1v[mi] = sp[32];
        }
        stage(2 * p + 2, (base + 2) & 3);
        stage(2 * p + 3, (base + 3) & 3);

#pragma unroll
        for (int mi = 0; mi < MPP; ++mi) {
            floatx16 P[2][2] = {};
#pragma unroll
            for (int kl = 0; kl < KK; ++kl) {
                const int pkk  = mi * KK + kl;     // 0..7 within phase
                const int slot = pkk & 1;
                P[0][0] = __builtin_amdgcn_mfma_f32_32x32x16_bf16(bbuf[slot][0], xk[0][kl], P[0][0], 0, 0, 0);
                P[1][0] = __builtin_amdgcn_mfma_f32_32x32x16_bf16(bbuf[slot][0], xk[1][kl], P[1][0], 0, 0, 0);
                P[0][1] = __builtin_amdgcn_mfma_f32_32x32x16_bf16(bbuf[slot][1], xk[0][kl], P[0][1], 0, 0, 0);
                P[1][1] = __builtin_amdgcn_mfma_f32_32x32x16_bf16(bbuf[slot][1], xk[1][kl], P[1][1], 0, 0, 0);
                {   // prefetch 2 pkk ahead (frag/unit-offset compile-time)
                    const int f  = (pkk + 2) & 3;
                    const int uo = (pkk + 2) >> 2;       // 0,1,2
                    const int sb = (base + uo) & 3;
                    bbuf[slot][0] = ldfrag(sb, f, cbg0);
                    bbuf[slot][1] = ldfrag(sb, f, cbg1);
                }
                if (pkk == 1) vmwait<G1>();    // prior phase's stages retired
                if (pkk == 5) vmwait<4>();     // u+2 resident before pkk6 read
            }
            if (mi == MPP - 1) asm volatile("s_setprio 0");
            // epilogue: acc += s_m * P (float2 -> v_pk_fma_f32)
#pragma unroll
            for (int t = 0; t < 2; ++t) {
                const float sv = (t == 0) ? s0v[mi] : s1v[mi];
                floatx2 s2 = {sv, sv};
#pragma unroll
                for (int cbp = 0; cbp < 2; ++cbp) {
                    floatx2*       A = (floatx2*)&acc[t][cbp];
                    const floatx2* Q = (const floatx2*)&P[t][cbp];
#pragma unroll
                    for (int i = 0; i < 8; ++i) A[i] += s2 * Q[i];
                }
            }
        }
    }
}

// ---------------------------------------------------------------------------
// Fused 3-layer CIN kernel. Block = 256 thr = 4 waves (2x2), 2 batches x all
// 128 l's per block; grid 1024 = 2 blocks/CU. X intermediates NEVER touch
// global: layer-boundary LDS exchange in slots 0-1; ps fused per layer.
// NOTE: (256,2) -> 256 unified regs/wave. (512,4)/(256,4)/(256,3) all
// spilled or regressed. Do not revisit.
// ---------------------------------------------------------------------------
__global__ __launch_bounds__(256, 2) void k_cin(
    const float* __restrict__ x,               // fp32 [B][MF][DDIM]
    const unsigned short* __restrict__ W0t,    // bf16 [MF][4][4][64][8] (padded)
    const unsigned short* __restrict__ W1t,    // bf16 [MF][8][4][64][8]
    const unsigned short* __restrict__ W2t,    // bf16 [MF][8][4][64][8]
    float* __restrict__ out)                   // fp32 [B][384]
{
    __shared__ unsigned short slab[4][8192];   // 4 x 16 KB W-ring; slots 0-1
                                               // double as the 32 KB X-exchange
    unsigned short* slabf = &slab[0][0];

    const int tid  = threadIdx.x;
    const int lane = tid & 63, wave = tid >> 6;
    const int hf   = lane >> 5, r31 = lane & 31;
    const int rowhalf = wave >> 1, colhalf = wave & 1;
    const int b = blockIdx.x * 2 + rowhalf;    // this wave's batch
    const int cbg0 = colhalf * 2, cbg1 = colhalf * 2 + 1;

    bf16x8   xk[2][8];                         // B-operand fragments
    floatx16 acc[2][2];                        // [t(row-tile)][cbp], D[l,row]

    // ---- ps: out[b][OFF+l] = sum over all 64 d (butterfly across lanes) ----
    auto write_ps = [&](int OFF) {
#pragma unroll
        for (int cbp = 0; cbp < 2; ++cbp) {
#pragma unroll
            for (int j = 0; j < 16; ++j) {
                float v = acc[0][cbp][j] + acc[1][cbp][j];
                v += __shfl_xor(v, 16);
                v += __shfl_xor(v, 8);
                v += __shfl_xor(v, 4);
                v += __shfl_xor(v, 2);
                v += __shfl_xor(v, 1);
                if (r31 == 0)
                    out[(size_t)b * 384 + OFF + (colhalf * 2 + cbp) * 32 +
                        (j & 3) + 8 * (j >> 2) + 4 * hf] = v;
            }
        }
    };

    // ---- layer boundary: acc -> LDS (reader frag order) -> xk ----
    // Writer element: row = t*32+r31, l = colhalf*64 + cbp*32 + 8g + 4hf + i
    //   => kk = colhalf*4 + cbp*2 + (g>>1), hfr = g&1, j = 4hf+i
    // Xf addr (shorts): rowhalf*8192 + ((t*8+kk)*64 + hfr*32 + r31)*8 + 4hf
    auto exchange = [&]() {
        vmwait<0>();                           // drain ring staging + ps stores
        barrier_raw();
#pragma unroll
        for (int t = 0; t < 2; ++t)
#pragma unroll
            for (int cbp = 0; cbp < 2; ++cbp)
#pragma unroll
                for (int g = 0; g < 4; ++g) {
                    unsigned short o[4];
#pragma unroll
                    for (int i = 0; i < 4; ++i) o[i] = f32_to_bf16(acc[t][cbp][g * 4 + i]);
                    const int kk  = colhalf * 4 + cbp * 2 + (g >> 1);
                    const int hfr = g & 1;
                    *(short4_t*)(&slabf[(size_t)rowhalf * 8192 +
                        ((size_t)(t * 8 + kk) * 64 + hfr * 32 + r31) * 8 + 4 * hf]) =
                        *(const short4_t*)o;
                }
        lgkmwait0();                           // writes committed to LDS
        barrier_raw();
#pragma unroll
        for (int t = 0; t < 2; ++t)
#pragma unroll
            for (int kk = 0; kk < 8; ++kk)
                xk[t][kk] = __builtin_bit_cast(bf16x8, *(const short8*)(
                    &slabf[(size_t)rowhalf * 8192 + ((size_t)(t * 8 + kk) * 64 + lane) * 8]));
        lgkmwait0();                           // reads in regs before restaging
        barrier_raw();
    };

    // ---- layer 0: xk from original x (KK=4 padded, h<MF else 0) ----
#pragma unroll
    for (int t = 0; t < 2; ++t)
#pragma unroll
        for (int kk = 0; kk < 4; ++kk) {
            unsigned short tmp[8];
#pragma unroll
            for (int j = 0; j < 8; ++j) {
                int h = kk * 16 + hf * 8 + j;
                float v = (h < MF) ? x[((size_t)b * MF + h) * DDIM + t * 32 + r31] : 0.f;
                tmp[j] = f32_to_bf16(v);
            }
            xk[t][kk] = __builtin_bit_cast(bf16x8, *(const short8*)tmp);
        }

    layer_loop<4>(W0t, x, b, lane, hf, r31, cbg0, cbg1, slabf, xk, acc);
    write_ps(0);
    exchange();

    layer_loop<8>(W1t, x, b, lane, hf, r31, cbg0, cbg1, slabf, xk, acc);
    write_ps(128);
    exchange();

    layer_loop<8>(W2t, x, b, lane, hf, r31, cbg0, cbg1, slabf, xk, acc);
    write_ps(256);
}

// ---------------------------------------------------------------------------
extern "C" void kernel_launch(void* const* d_in, const int* in_sizes, int n_in,
                              void* d_out, int out_size, void* d_ws, size_t ws_size,
                              hipStream_t stream) {
    const float* x  = (const float*)d_in[0];
    const float* W0 = (const float*)d_in[1];
    const float* W1 = (const float*)d_in[2];
    const float* W2 = (const float*)d_in[3];
    float* out = (float*)d_out;

    char* ws = (char*)d_ws;
    size_t off = 0;
    auto alloc = [&](size_t bytes) -> void* {
        void* p = ws + off;
        off += (bytes + 255) & ~(size_t)255;
        return p;
    };
    unsigned short* W0t = (unsigned short*)alloc((size_t)MF * 4 * 2048 * 2);   // 0.66 MB
    unsigned short* W1t = (unsigned short*)alloc((size_t)MF * 8 * 2048 * 2);   // 1.31 MB
    unsigned short* W2t = (unsigned short*)alloc((size_t)MF * 8 * 2048 * 2);   // 1.31 MB

    k_wprep_all<<<800, 256, 0, stream>>>(W0, W1, W2, W0t, W1t, W2t);
    k_cin<<<ROWS / 128, 256, 0, stream>>>(x, W0t, W1t, W2t, out);
}

// Round 8
// 410.810 us; speedup vs baseline: 2.6126x; 1.0539x over previous
//
#include <hip/hip_runtime.h>
#include <hip/hip_bf16.h>
#include <cstdint>

// Problem constants
#define BATCH 2048
#define MF    40                 // num fields
#define DDIM  64                 // embedding dim
#define LDIM  128                // hidden size per CIN layer
#define ROWS  (BATCH * DDIM)     // 131072 (b,d) rows

typedef __attribute__((ext_vector_type(4)))  short    short4_t;
typedef __attribute__((ext_vector_type(8)))  short    short8;
typedef __attribute__((ext_vector_type(8)))  __bf16   bf16x8;
typedef __attribute__((ext_vector_type(2)))  float    floatx2;
typedef __attribute__((ext_vector_type(4)))  float    floatx4;
typedef __attribute__((ext_vector_type(16))) float    floatx16;

// POST-MORTEM LEDGER (do not revisit):
//  R1: t-split 4-blocks/CU REGRESSED 380->470 (halved per-wave tile -> 2x LDS
//      traffic, 4x barriers, spill at 128-reg cap).
//  R2: NT hints REGRESSED (scattered NT dword stores -> partial-line writes).
//  R3: anti-phase stagger NEUTRAL; zero-C MFMA init NEUTRAL.
//  R4: ring-3 + launch_bounds(256,3) CATASTROPHIC (runtime slot bases ->
//      spill). Ring addressing must be compile-time; reg cap <256 spills.
//  R5: __builtin_nontemporal_load needs clang ext_vector types.
//  R6: coalesced wprep landed; ~55us bench-minus-k_cin gap is fixed harness
//      overhead. Cross-session noise +-2-3% on identical code.
//  R7: 2-unit phases (barrier every 32 MFMAs) NEUTRAL -> per-unit barrier
//      overhead is NOT the constraint. Reverted to R0 unit body.
//  Invariant R0-R7: per-wave T~2280 cyc/unit vs ~300 cyc issued work; all
//      shared resources <50% utilized; MfmaUtil 52-55 regardless of
//      scheduling micro-structure.
//  R8 (this round): MERGED BLOCK. 8 waves (512 thr) x 4 batches share ONE
//      W-ring (was 2x 4-wave blocks staging identical W separately).
//      Per-wave code byte-identical; staging/CU halves; 16 waves/CU
//      (LDS 64KB x2, VGPR 120<=128). launch_bounds(512,2) keeps the 256-reg
//      cap (the old "(512,4) spilled" was the ,4 cap). stage()=2 insts ->
//      GATE rescaled by the proven per-m-issue formula (KK=8:6, KK=4:4),
//      prologue drain vmcnt(2). Exchange overlay = all 4 slots (ring fully
//      drained at layer boundary). MFMA order per batch unchanged.

__device__ __forceinline__ unsigned short f32_to_bf16(float f) {
    union { float f; uint32_t u; } v; v.f = f;
    uint32_t u = v.u;
    uint32_t r = (u + 0x7fffu + ((u >> 16) & 1u)) >> 16;   // RNE
    return (unsigned short)r;
}

// raw barrier: execution sync WITHOUT __syncthreads' vmcnt(0)/lgkmcnt(0) drain
__device__ __forceinline__ void barrier_raw() {
    asm volatile("s_barrier" ::: "memory");
}
__device__ __forceinline__ void lgkmwait0() {
    asm volatile("s_waitcnt lgkmcnt(0)" ::: "memory");
}
template <int N> __device__ __forceinline__ void vmwait() {
    if constexpr (N == 0)  asm volatile("s_waitcnt vmcnt(0)"  ::: "memory");
    if constexpr (N == 2)  asm volatile("s_waitcnt vmcnt(2)"  ::: "memory");
    if constexpr (N == 4)  asm volatile("s_waitcnt vmcnt(4)"  ::: "memory");
    if constexpr (N == 6)  asm volatile("s_waitcnt vmcnt(6)"  ::: "memory");
}

// ---------------------------------------------------------------------------
// W prep, coalesced (R6, working). One block per (layer, m, kk) 16h x 128l
// tile: 800 x 256. floatx4 NT load -> bf16 LDS tile -> short8 store.
//   Wt[m][kk][cb][lane][j] = W[m][ kk*16 + (lane>>5)*8 + j ][ cb*32 + (lane&31) ]
// W0 padded to KK=4 (h in [40,64) -> 0).
// ---------------------------------------------------------------------------
__global__ __launch_bounds__(256) void k_wprep_all(
    const float* __restrict__ W0, const float* __restrict__ W1,
    const float* __restrict__ W2,
    unsigned short* __restrict__ W0t,
    unsigned short* __restrict__ W1t,
    unsigned short* __restrict__ W2t) {
    __shared__ unsigned short t16[16 * 128];   // bf16 tile [h_local][l]

    int bi = blockIdx.x;                 // W0: 160 tiles, W1/W2: 320 each
    const float* W; unsigned short* Wt; int KK, H;
    if (bi < 160)      { W = W0; Wt = W0t; KK = 4; H = 40; }
    else if (bi < 480) { bi -= 160; W = W1; Wt = W1t; KK = 8; H = 128; }
    else               { bi -= 480; W = W2; Wt = W2t; KK = 8; H = 128; }
    const int tid = threadIdx.x;
    const int kk = bi % KK, m = bi / KK;

#pragma unroll
    for (int half = 0; half < 2; ++half) {
        const int idx = half * 1024 + tid * 4;      // tile-linear f32 index
        const int hl  = idx >> 7, l = idx & 127;
        const int hg  = kk * 16 + hl;
        floatx4 v = {0.f, 0.f, 0.f, 0.f};
        if (hg < H)
            v = __builtin_nontemporal_load(
                (const floatx4*)&W[((size_t)m * H + hg) * LDIM + l]);
        unsigned short o[4];
        o[0] = f32_to_bf16(v.x); o[1] = f32_to_bf16(v.y);
        o[2] = f32_to_bf16(v.z); o[3] = f32_to_bf16(v.w);
        *(short4_t*)&t16[idx] = *(const short4_t*)o;
    }
    __syncthreads();

    const int lane = tid & 63, cb = tid >> 6;
    const int l  = cb * 32 + (lane & 31);
    const int hb = (lane >> 5) * 8;
    unsigned short o[8];
#pragma unroll
    for (int j = 0; j < 8; ++j) o[j] = t16[(hb + j) * 128 + l];
    *(short8*)(Wt + (((size_t)(m * KK + kk) * 4 + cb) * 64 + lane) * 8) =
        *(const short8*)o;
}

// ---------------------------------------------------------------------------
// One layer's K-loop: the proven R0 ring-4 / raw-barrier / counted-vmcnt
// body, 512-thread staging. stage() = 2 x global_load_lds (512 thr x 16 B
// x 2 = 16 KB). GATE = per-m vmem issue count (proven R0 formula, rescaled):
// KK=8: 2 scales + 2 units x 2 insts = 6; KK=4: 2 + 2 = 4.
// Prologue: 3 stages (6 insts), vmcnt(2) -> units 0,1 resident.
// ---------------------------------------------------------------------------
template <int KK>
__device__ __forceinline__ void layer_loop(
    const unsigned short* __restrict__ Wt,     // bf16 [MF][KK][4][64][8]
    const float* __restrict__ x, int b,
    int lane, int hf, int r31, int cbg0, int cbg1,
    unsigned short* slabf,                     // 4 slots x 8192 shorts
    bf16x8 (&xk)[2][8], floatx16 (&acc)[2][2])
{
    constexpr int UPM  = KK / 4;               // units per m
    constexpr int NU   = MF * UPM;             // total units (16 KB each)
    constexpr int GATE = (KK == 8) ? 6 : 4;    // = vmem insts per m (uniform)

    auto stage = [&](int uu) {                 // stage unit uu (clamped: same bytes)
        int u = uu < NU ? uu : NU - 1;
        const unsigned short* src = Wt + (size_t)u * 8192;
        const int tid = threadIdx.x;
#pragma unroll
        for (int it = 0; it < 2; ++it) {
            int c = it * 512 + tid;
            __builtin_amdgcn_global_load_lds(
                (const __attribute__((address_space(1))) uint32_t*)(src + (size_t)c * 8),
                (__attribute__((address_space(3))) uint32_t*)(&slabf[(size_t)(u & 3) * 8192 + (size_t)c * 8]),
                16, 0, 0);
        }
    };
    auto ldfrag = [&](int u, int frag, int cb) {
        return __builtin_bit_cast(bf16x8, *(const short8*)(
            &slabf[(size_t)(u & 3) * 8192 + ((size_t)(frag * 4 + cb) * 64 + lane) * 8]));
    };

    acc[0][0] = floatx16{}; acc[0][1] = floatx16{};
    acc[1][0] = floatx16{}; acc[1][1] = floatx16{};

    // prologue: fill 3 ring slots; units 0,1 retired before priming
    vmwait<0>();
    stage(0); stage(1); stage(2);
    vmwait<2>();
    barrier_raw();

    bf16x8 bbuf[2][2];                         // W A-frag register ring
#pragma unroll
    for (int p = 0; p < 2; ++p) {
        bbuf[p][0] = ldfrag(0, p, cbg0);
        bbuf[p][1] = ldfrag(0, p, cbg1);
    }

    float s0v = 0.f, s1v = 0.f;

#pragma unroll 1
    for (int m = 0; m < MF; ++m) {
        floatx16 P[2][2] = {};
#pragma unroll
        for (int kk = 0; kk < KK; ++kk) {
            if (kk % 4 == 0) {                 // unit top
                barrier_raw();
                asm volatile("s_setprio 1");
                if (kk == 0) {                 // 2 per-lane scalar scale loads
                    const float* sp = x + ((size_t)b * MF + m) * DDIM + r31;
                    s0v = sp[0];
                    s1v = sp[32];
                }
                stage(m * UPM + kk / 4 + 3);   // 3 units ahead in the ring
            }
            const int slot = kk & 1;
            P[0][0] = __builtin_amdgcn_mfma_f32_32x32x16_bf16(bbuf[slot][0], xk[0][kk], P[0][0], 0, 0, 0);
            P[1][0] = __builtin_amdgcn_mfma_f32_32x32x16_bf16(bbuf[slot][0], xk[1][kk], P[1][0], 0, 0, 0);
            P[0][1] = __builtin_amdgcn_mfma_f32_32x32x16_bf16(bbuf[slot][1], xk[0][kk], P[0][1], 0, 0, 0);
            P[1][1] = __builtin_amdgcn_mfma_f32_32x32x16_bf16(bbuf[slot][1], xk[1][kk], P[1][1], 0, 0, 0);
            {   // prefetch 2 kk ahead (crosses unit/m boundary; all compile-time)
                const int j  = kk + 2;
                int mm = m + ((j >= KK) ? 1 : 0);
                if (mm > MF - 1) mm = MF - 1;
                const int jj = (j >= KK) ? (j - KK) : j;
                const int u  = mm * UPM + jj / 4;
                bbuf[slot][0] = ldfrag(u, jj % 4, cbg0);
                bbuf[slot][1] = ldfrag(u, jj % 4, cbg1);
            }
            if (kk % 4 == 3) vmwait<GATE>();   // uniform end-of-unit gate
        }
        asm volatile("s_setprio 0");
        // epilogue: acc += s_t * P (float2 -> v_pk_fma_f32)
#pragma unroll
        for (int t = 0; t < 2; ++t) {
            const float sv = (t == 0) ? s0v : s1v;
            floatx2 s2 = {sv, sv};
#pragma unroll
            for (int cbp = 0; cbp < 2; ++cbp) {
                floatx2*       A = (floatx2*)&acc[t][cbp];
                const floatx2* Q = (const floatx2*)&P[t][cbp];
#pragma unroll
                for (int i = 0; i < 8; ++i) A[i] += s2 * Q[i];
            }
        }
    }
}

// ---------------------------------------------------------------------------
// Fused 3-layer CIN kernel, MERGED BLOCK (R8). Block = 512 thr = 8 waves
// (4 batches x 2 l-halves), ONE shared W-ring; grid 512 = 2 blocks/CU =
// 16 waves/CU. Per-wave code identical to R0's proven body; staging per CU
// halves (one 16 KB stage feeds 8 waves). X intermediates never touch
// global: layer-boundary exchange overlays ALL FOUR ring slots (4 batches x
// 16 KB; ring fully drained at boundary). ps fused per layer.
// NOTE: launch_bounds 2nd arg MUST stay 2 (256-reg cap); ,3 / ,4 spill this
// body (R4 + old session). Ring addressing must stay compile-time (u&3).
// ---------------------------------------------------------------------------
__global__ __launch_bounds__(512, 2) void k_cin(
    const float* __restrict__ x,               // fp32 [B][MF][DDIM]
    const unsigned short* __restrict__ W0t,    // bf16 [MF][4][4][64][8] (padded)
    const unsigned short* __restrict__ W1t,    // bf16 [MF][8][4][64][8]
    const unsigned short* __restrict__ W2t,    // bf16 [MF][8][4][64][8]
    float* __restrict__ out)                   // fp32 [B][384]
{
    __shared__ unsigned short slab[4][8192];   // 4 x 16 KB W-ring; all 4 slots
                                               // double as the 64 KB X-exchange
    unsigned short* slabf = &slab[0][0];

    const int tid  = threadIdx.x;
    const int lane = tid & 63, wave = tid >> 6;
    const int hf   = lane >> 5, r31 = lane & 31;
    const int rowhalf = wave >> 1, colhalf = wave & 1;   // rowhalf in [0,4)
    const int b = blockIdx.x * 4 + rowhalf;    // this wave's batch
    const int cbg0 = colhalf * 2, cbg1 = colhalf * 2 + 1;

    bf16x8   xk[2][8];                         // B-operand fragments
    floatx16 acc[2][2];                        // [t(row-tile)][cbp], D[l,row]

    // ---- ps: out[b][OFF+l] = sum over all 64 d (butterfly across lanes) ----
    auto write_ps = [&](int OFF) {
#pragma unroll
        for (int cbp = 0; cbp < 2; ++cbp) {
#pragma unroll
            for (int j = 0; j < 16; ++j) {
                float v = acc[0][cbp][j] + acc[1][cbp][j];
                v += __shfl_xor(v, 16);
                v += __shfl_xor(v, 8);
                v += __shfl_xor(v, 4);
                v += __shfl_xor(v, 2);
                v += __shfl_xor(v, 1);
                if (r31 == 0)
                    out[(size_t)b * 384 + OFF + (colhalf * 2 + cbp) * 32 +
                        (j & 3) + 8 * (j >> 2) + 4 * hf] = v;
            }
        }
    };

    // ---- layer boundary: acc -> LDS (reader frag order) -> xk ----
    // Writer element: row = t*32+r31, l = colhalf*64 + cbp*32 + 8g + 4hf + i
    //   => kk = colhalf*4 + cbp*2 + (g>>1), hfr = g&1, j = 4hf+i
    // Xf addr (shorts): rowhalf*8192 + ((t*8+kk)*64 + hfr*32 + r31)*8 + 4hf
    // rowhalf in [0,4): 4 x 16 KB regions = the whole 64 KB slab.
    auto exchange = [&]() {
        vmwait<0>();                           // drain ring staging + ps stores
        barrier_raw();
#pragma unroll
        for (int t = 0; t < 2; ++t)
#pragma unroll
            for (int cbp = 0; cbp < 2; ++cbp)
#pragma unroll
                for (int g = 0; g < 4; ++g) {
                    unsigned short o[4];
#pragma unroll
                    for (int i = 0; i < 4; ++i) o[i] = f32_to_bf16(acc[t][cbp][g * 4 + i]);
                    const int kk  = colhalf * 4 + cbp * 2 + (g >> 1);
                    const int hfr = g & 1;
                    *(short4_t*)(&slabf[(size_t)rowhalf * 8192 +
                        ((size_t)(t * 8 + kk) * 64 + hfr * 32 + r31) * 8 + 4 * hf]) =
                        *(const short4_t*)o;
                }
        lgkmwait0();                           // writes committed to LDS
        barrier_raw();
#pragma unroll
        for (int t = 0; t < 2; ++t)
#pragma unroll
            for (int kk = 0; kk < 8; ++kk)
                xk[t][kk] = __builtin_bit_cast(bf16x8, *(const short8*)(
                    &slabf[(size_t)rowhalf * 8192 + ((size_t)(t * 8 + kk) * 64 + lane) * 8]));
        lgkmwait0();                           // reads in regs before restaging
        barrier_raw();
    };

    // ---- layer 0: xk from original x (KK=4 padded, h<MF else 0) ----
#pragma unroll
    for (int t = 0; t < 2; ++t)
#pragma unroll
        for (int kk = 0; kk < 4; ++kk) {
            unsigned short tmp[8];
#pragma unroll
            for (int j = 0; j < 8; ++j) {
                int h = kk * 16 + hf * 8 + j;
                float v = (h < MF) ? x[((size_t)b * MF + h) * DDIM + t * 32 + r31] : 0.f;
                tmp[j] = f32_to_bf16(v);
            }
            xk[t][kk] = __builtin_bit_cast(bf16x8, *(const short8*)tmp);
        }

    layer_loop<4>(W0t, x, b, lane, hf, r31, cbg0, cbg1, slabf, xk, acc);
    write_ps(0);
    exchange();

    layer_loop<8>(W1t, x, b, lane, hf, r31, cbg0, cbg1, slabf, xk, acc);
    write_ps(128);
    exchange();

    layer_loop<8>(W2t, x, b, lane, hf, r31, cbg0, cbg1, slabf, xk, acc);
    write_ps(256);
}

// ---------------------------------------------------------------------------
extern "C" void kernel_launch(void* const* d_in, const int* in_sizes, int n_in,
                              void* d_out, int out_size, void* d_ws, size_t ws_size,
                              hipStream_t stream) {
    const float* x  = (const float*)d_in[0];
    const float* W0 = (const float*)d_in[1];
    const float* W1 = (const float*)d_in[2];
    const float* W2 = (const float*)d_in[3];
    float* out = (float*)d_out;

    char* ws = (char*)d_ws;
    size_t off = 0;
    auto alloc = [&](size_t bytes) -> void* {
        void* p = ws + off;
        off += (bytes + 255) & ~(size_t)255;
        return p;
    };
    unsigned short* W0t = (unsigned short*)alloc((size_t)MF * 4 * 2048 * 2);   // 0.66 MB
    unsigned short* W1t = (unsigned short*)alloc((size_t)MF * 8 * 2048 * 2);   // 1.31 MB
    unsigned short* W2t = (unsigned short*)alloc((size_t)MF * 8 * 2048 * 2);   // 1.31 MB

    k_wprep_all<<<800, 256, 0, stream>>>(W0, W1, W2, W0t, W1t, W2t);
    k_cin<<<ROWS / 256, 512, 0, stream>>>(x, W0t, W1t, W2t, out);
}